// Round 1
// baseline (68.795 us; speedup 1.0000x reference)
//
#include <hip/hip_runtime.h>

// Sizes fixed by the reference setup.
#define SLEN 1024   // S
#define BATCH 32    // B
#define DIM 1024    // D = 2H

// k1: g[b,d] = sum_e h[b,e] * W[e,d]   (h = hidden flat-reshaped to [B, D])
// Grid: (D/256, B, 8 e-chunks of 128). Coalesced W row reads, atomic K-split.
__global__ void k1_gW(const float* __restrict__ hid, const float* __restrict__ W,
                      float* __restrict__ g) {
    const int d  = blockIdx.x * 256 + threadIdx.x;
    const int b  = blockIdx.y;
    const int e0 = blockIdx.z * 128;
    const float* hrow = hid + b * DIM;
    float acc = 0.f;
    #pragma unroll 4
    for (int e = e0; e < e0 + 128; ++e)
        acc += hrow[e] * W[(size_t)e * DIM + d];
    atomicAdd(&g[b * DIM + d], acc);
}

// k2: logits[b,s] = dot(enc[s,b,:], g[b,:]).  One 64-lane wave per (s,b) row.
__global__ void k2_logits(const float* __restrict__ enc, const float* __restrict__ g,
                          float* __restrict__ logits) {
    const int wave = (int)((blockIdx.x * (size_t)blockDim.x + threadIdx.x) >> 6);
    const int lane = threadIdx.x & 63;
    // rows of enc are (s,b) with b fastest: row index == wave
    const int b = wave & (BATCH - 1);
    const int s = wave >> 5;
    const float4* ep = (const float4*)(enc + (size_t)wave * DIM);
    const float4* gp = (const float4*)(g + b * DIM);
    float acc = 0.f;
    #pragma unroll
    for (int it = 0; it < 4; ++it) {
        float4 e  = ep[lane + it * 64];
        float4 gg = gp[lane + it * 64];
        acc += e.x * gg.x + e.y * gg.y + e.z * gg.z + e.w * gg.w;
    }
    #pragma unroll
    for (int off = 32; off > 0; off >>= 1)
        acc += __shfl_down(acc, off, 64);
    if (lane == 0) logits[b * SLEN + s] = acc;
}

// k3: row softmax over S per batch. One block per b.
// (Linear bias `bias` adds a per-b constant to every logit -> cancels in softmax;
//  it is also all-zeros in setup_inputs. Dropped.)
__global__ void k3_softmax(const float* __restrict__ logits, float* __restrict__ alpha) {
    const int b = blockIdx.x;
    const int tid = threadIdx.x;
    __shared__ float red[256];
    float v[4];
    float m = -3.0e38f;
    #pragma unroll
    for (int i = 0; i < 4; ++i) {
        v[i] = logits[b * SLEN + tid + i * 256];
        m = fmaxf(m, v[i]);
    }
    red[tid] = m; __syncthreads();
    for (int off = 128; off > 0; off >>= 1) {
        if (tid < off) red[tid] = fmaxf(red[tid], red[tid + off]);
        __syncthreads();
    }
    m = red[0]; __syncthreads();
    float sum = 0.f;
    #pragma unroll
    for (int i = 0; i < 4; ++i) { v[i] = expf(v[i] - m); sum += v[i]; }
    red[tid] = sum; __syncthreads();
    for (int off = 128; off > 0; off >>= 1) {
        if (tid < off) red[tid] += red[tid + off];
        __syncthreads();
    }
    const float inv = 1.f / red[0];
    #pragma unroll
    for (int i = 0; i < 4; ++i)
        alpha[b * SLEN + tid + i * 256] = v[i] * inv;
}

// k4: reps[b,d] = sum_s alpha[b,s] * enc[s,b,d].  s-split with atomics.
__global__ void k4_reps(const float* __restrict__ enc, const float* __restrict__ alpha,
                        float* __restrict__ reps) {
    const int d  = blockIdx.x * 256 + threadIdx.x;
    const int b  = blockIdx.y;
    const int s0 = blockIdx.z * 128;
    float acc = 0.f;
    #pragma unroll 4
    for (int s = s0; s < s0 + 128; ++s)
        acc += alpha[b * SLEN + s] * enc[((size_t)s * BATCH + b) * DIM + d];
    atomicAdd(&reps[b * DIM + d], acc);
}

extern "C" void kernel_launch(void* const* d_in, const int* in_sizes, int n_in,
                              void* d_out, int out_size, void* d_ws, size_t ws_size,
                              hipStream_t stream) {
    const float* hid = (const float*)d_in[0];  // (2,B,H) flat == h[B, D]
    const float* enc = (const float*)d_in[1];  // (S,B,D)
    const float* W   = (const float*)d_in[2];  // (D,D), energy = enc @ W.T
    // d_in[3] = bias (D,), zeros; cancels in softmax -> unused.

    float* out   = (float*)d_out;
    float* reps  = out;               // [B,1,D] -> B*D floats
    float* alpha = out + BATCH * DIM; // [B,1,S] -> B*S floats

    float* g      = (float*)d_ws;        // B*D
    float* logits = g + BATCH * DIM;     // B*S

    hipMemsetAsync(g, 0, BATCH * DIM * sizeof(float), stream);
    hipMemsetAsync(reps, 0, BATCH * DIM * sizeof(float), stream);

    k1_gW<<<dim3(DIM / 256, BATCH, 8), 256, 0, stream>>>(hid, W, g);
    k2_logits<<<dim3((SLEN * BATCH) / 4), 256, 0, stream>>>(enc, g, logits);
    k3_softmax<<<BATCH, 256, 0, stream>>>(logits, alpha);
    k4_reps<<<dim3(DIM / 256, BATCH, 8), 256, 0, stream>>>(enc, alpha, reps);
}

// Round 2
// 51.069 us; speedup vs baseline: 1.3471x; 1.3471x over previous
//
#include <hip/hip_runtime.h>

#define S 1024
#define B 32
#define D 1024
#define NCH 32          // s-chunks in fused kernel
#define CH (S / NCH)    // 32 rows per block
#define ECH 16          // e-chunks in k1
#define EC (D / ECH)    // 64 e per chunk

// k1: g[b,d] = sum_e h[b,e] * W[e,d].  W read exactly once (4 MB).
// Grid (D/256, ECH). Each thread owns one d, accumulates all 32 batches
// over a 64-wide e-chunk staged in LDS, then atomically adds (g pre-zeroed).
__global__ __launch_bounds__(256) void k1_gW(const float* __restrict__ hid,
                                             const float* __restrict__ W,
                                             float* __restrict__ g) {
    const int tid = threadIdx.x;
    const int d   = blockIdx.x * 256 + tid;
    const int e0  = blockIdx.y * EC;
    __shared__ float4 sh[EC * 8];          // [e][j], j-th float4 = batches 4j..4j+3
    for (int k = 0; k < (EC * 32) / 256; ++k) {
        int lin = tid + k * 256;
        int b = lin >> 6;                  // EC == 64
        int e = lin & (EC - 1);
        ((float*)sh)[e * 32 + b] = hid[b * D + e0 + e];
    }
    __syncthreads();
    float acc[32];
    #pragma unroll
    for (int b = 0; b < 32; ++b) acc[b] = 0.f;
    for (int e = 0; e < EC; ++e) {
        float w = W[(size_t)(e0 + e) * D + d];
        #pragma unroll
        for (int j = 0; j < 8; ++j) {
            float4 hv = sh[e * 8 + j];     // broadcast read, conflict-free
            acc[4 * j + 0] += hv.x * w;
            acc[4 * j + 1] += hv.y * w;
            acc[4 * j + 2] += hv.z * w;
            acc[4 * j + 3] += hv.w * w;
        }
    }
    #pragma unroll
    for (int b = 0; b < 32; ++b) atomicAdd(&g[b * D + d], acc[b]);
}

// k2: fused logits + online-softmax + partial weighted sum. enc read ONCE.
// Grid (NCH, B); block handles CH s-rows of batch b. Per thread: float4 of d.
__global__ __launch_bounds__(256) void k2_fused(const float* __restrict__ enc,
                                                const float* __restrict__ g,
                                                float* __restrict__ logits,
                                                float* __restrict__ marr,
                                                float* __restrict__ larr,
                                                float* __restrict__ pacc) {
    const int tid  = threadIdx.x;
    const int c    = blockIdx.x;
    const int b    = blockIdx.y;
    const int lane = tid & 63;
    const int wid  = tid >> 6;
    __shared__ float red[2][4];            // double-buffered cross-wave reduce
    const float4 gv = ((const float4*)(g + b * D))[tid];
    const float4* encb = (const float4*)enc;
    size_t base = ((size_t)(c * CH) * B + b) * (D / 4) + tid;
    float4 ecur = encb[base];
    float m = -3.0e38f, l = 0.f;
    float4 acc = {0.f, 0.f, 0.f, 0.f};
    for (int i = 0; i < CH; ++i) {
        float4 enx = ecur;
        if (i + 1 < CH) enx = encb[base + (size_t)(i + 1) * B * (D / 4)];  // prefetch
        float pd = ecur.x * gv.x + ecur.y * gv.y + ecur.z * gv.z + ecur.w * gv.w;
        #pragma unroll
        for (int off = 32; off > 0; off >>= 1)
            pd += __shfl_down(pd, off, 64);
        if (lane == 0) red[i & 1][wid] = pd;
        __syncthreads();
        float logit = red[i & 1][0] + red[i & 1][1] + red[i & 1][2] + red[i & 1][3];
        if (tid == 0) logits[b * S + c * CH + i] = logit;
        float mn = fmaxf(m, logit);
        float sc = __expf(m - mn);
        float p  = __expf(logit - mn);
        l = l * sc + p;
        acc.x = acc.x * sc + p * ecur.x;
        acc.y = acc.y * sc + p * ecur.y;
        acc.z = acc.z * sc + p * ecur.z;
        acc.w = acc.w * sc + p * ecur.w;
        m = mn;
        ecur = enx;
    }
    ((float4*)pacc)[(size_t)(c * B + b) * (D / 4) + tid] = acc;
    if (tid == 0) { marr[c * B + b] = m; larr[c * B + b] = l; }
}

// k3: merge per-chunk partials -> reps; normalize logits -> alpha.
// Grid (4, B): block covers 256 d's and 256 s's of batch b.
__global__ __launch_bounds__(256) void k3_combine(const float* __restrict__ logits,
                                                  const float* __restrict__ marr,
                                                  const float* __restrict__ larr,
                                                  const float* __restrict__ pacc,
                                                  float* __restrict__ out) {
    const int tid = threadIdx.x;
    const int q   = blockIdx.x;
    const int b   = blockIdx.y;
    __shared__ float shm[NCH], shl[NCH];
    if (tid < NCH) { shm[tid] = marr[tid * B + b]; shl[tid] = larr[tid * B + b]; }
    __syncthreads();
    float mg = -3.0e38f;
    #pragma unroll
    for (int c = 0; c < NCH; ++c) mg = fmaxf(mg, shm[c]);
    const int d = q * 256 + tid;
    float lg = 0.f, racc = 0.f;
    #pragma unroll 4
    for (int c = 0; c < NCH; ++c) {
        float fc = __expf(shm[c] - mg);
        lg   += shl[c] * fc;
        racc += pacc[(size_t)(c * B + b) * D + d] * fc;
    }
    float inv = 1.f / lg;
    out[b * D + d] = racc * inv;                                   // reps [B,1,D]
    int s = q * 256 + tid;
    out[B * D + b * S + s] = __expf(logits[b * S + s] - mg) * inv; // alpha [B,1,S]
}

extern "C" void kernel_launch(void* const* d_in, const int* in_sizes, int n_in,
                              void* d_out, int out_size, void* d_ws, size_t ws_size,
                              hipStream_t stream) {
    const float* hid = (const float*)d_in[0];  // (2,B,H) flat == h[B, D]
    const float* enc = (const float*)d_in[1];  // (S,B,D)
    const float* W   = (const float*)d_in[2];  // (D,D)
    // d_in[3] = bias: adds a per-b constant to every logit -> cancels in softmax.

    float* out = (float*)d_out;

    float* g      = (float*)d_ws;          // B*D
    float* logits = g + B * D;             // B*S
    float* marr   = logits + B * S;        // NCH*B
    float* larr   = marr + NCH * B;        // NCH*B
    float* pacc   = larr + NCH * B;        // NCH*B*D (4 MB)

    hipMemsetAsync(g, 0, B * D * sizeof(float), stream);
    k1_gW<<<dim3(D / 256, ECH), 256, 0, stream>>>(hid, W, g);
    k2_fused<<<dim3(NCH, B), 256, 0, stream>>>(enc, g, logits, marr, larr, pacc);
    k3_combine<<<dim3(4, B), 256, 0, stream>>>(logits, marr, larr, pacc, out);
}